// Round 1
// baseline (617.369 us; speedup 1.0000x reference)
//
#include <hip/hip_runtime.h>
#include <hip/hip_bf16.h>

// MHA forward: B=4, S=1024, D=1024, H=16, DK=64
// outputs: out [4,1024,1024] f32, attn [4,16,1024,1024] f32 (concat in d_out)

typedef __bf16 bf16_t;
typedef __bf16 bf16x4 __attribute__((ext_vector_type(4)));
typedef __bf16 bf16x8 __attribute__((ext_vector_type(8)));
typedef float f32x4 __attribute__((ext_vector_type(4)));

#define MFMA16(a, b, c) __builtin_amdgcn_mfma_f32_16x16x32_bf16(a, b, c, 0, 0, 0)

// ---------------------------------------------------------------- cast x -> bf16
__global__ __launch_bounds__(256) void cast_f32_bf16(const float* __restrict__ in,
                                                     bf16_t* __restrict__ out, int n4) {
    int i = blockIdx.x * blockDim.x + threadIdx.x;
    if (i >= n4) return;
    float4 v = reinterpret_cast<const float4*>(in)[i];
    bf16x4 o = { (bf16_t)v.x, (bf16_t)v.y, (bf16_t)v.z, (bf16_t)v.w };
    reinterpret_cast<bf16x4*>(out)[i] = o;
}

// ------------------------------------------- transpose + cast the 4 weight matrices
__global__ __launch_bounds__(1024) void transpose_cast_w(const float* __restrict__ w0,
                                                         const float* __restrict__ w1,
                                                         const float* __restrict__ w2,
                                                         const float* __restrict__ w3,
                                                         bf16_t* __restrict__ wt) {
    __shared__ float tile[32][33];
    const float* src = (blockIdx.z == 0) ? w0 : (blockIdx.z == 1) ? w1
                     : (blockIdx.z == 2) ? w2 : w3;
    bf16_t* dst = wt + (size_t)blockIdx.z * 1024 * 1024;
    int r0 = blockIdx.y * 32, c0 = blockIdx.x * 32;
    tile[threadIdx.y][threadIdx.x] = src[(size_t)(r0 + threadIdx.y) * 1024 + c0 + threadIdx.x];
    __syncthreads();
    dst[(size_t)(c0 + threadIdx.y) * 1024 + r0 + threadIdx.x] = (bf16_t)tile[threadIdx.x][threadIdx.y];
}

// ---------------------------------------------------------------- generic NT GEMM
// A: Mx1024 bf16 row-major (lda=1024), BT: 1024x1024 bf16 row-major (B transposed)
// one wave computes 16 rows x 64 cols; block = 4 waves = 64 rows x 64 cols
// MODE 0: store bf16, scale 0.125 (Q)   MODE 1: store bf16 (K)
// MODE 2: store bf16 transposed per head (V -> VT[b,h,dk,s])   MODE 3: store f32 (out)
template <int MODE>
__global__ __launch_bounds__(256) void gemm_nt(const bf16_t* __restrict__ A,
                                               const bf16_t* __restrict__ BT,
                                               void* __restrict__ out) {
    const int lane = threadIdx.x & 63;
    const int wave = threadIdx.x >> 6;
    const int m0 = (blockIdx.x * 4 + wave) * 16;
    const int n0 = blockIdx.y * 64;
    const int lr = lane & 15;
    const int lk = (lane >> 4) * 8;
    f32x4 acc[4] = {};
    const bf16_t* ap = A + (size_t)(m0 + lr) * 1024 + lk;
    const bf16_t* bp = BT + (size_t)(n0 + lr) * 1024 + lk;
    for (int kb = 0; kb < 1024; kb += 32) {
        bf16x8 a = *reinterpret_cast<const bf16x8*>(ap + kb);
#pragma unroll
        for (int f = 0; f < 4; ++f) {
            bf16x8 b = *reinterpret_cast<const bf16x8*>(bp + (size_t)f * 16 * 1024 + kb);
            acc[f] = MFMA16(a, b, acc[f]);
        }
    }
    const int rbase = m0 + (lane >> 4) * 4;
#pragma unroll
    for (int f = 0; f < 4; ++f) {
        const int col = n0 + f * 16 + lr;
#pragma unroll
        for (int r = 0; r < 4; ++r) {
            const int row = rbase + r;
            const float v = acc[f][r];
            if (MODE == 0) {
                ((bf16_t*)out)[(size_t)row * 1024 + col] = (bf16_t)(v * 0.125f);
            } else if (MODE == 1) {
                ((bf16_t*)out)[(size_t)row * 1024 + col] = (bf16_t)v;
            } else if (MODE == 2) {
                const int bb = row >> 10, s = row & 1023, h = col >> 6, d = col & 63;
                ((bf16_t*)out)[(((size_t)(bb * 16 + h) * 64 + d) << 10) + s] = (bf16_t)v;
            } else {
                ((float*)out)[(size_t)row * 1024 + col] = v;
            }
        }
    }
}

// -------------------------------------- scores: per head Q[1024,64] @ K^T + bias
__global__ __launch_bounds__(256) void scores_gemm(const bf16_t* __restrict__ qb,
                                                   const bf16_t* __restrict__ kbuf,
                                                   const float* __restrict__ bias,
                                                   float* __restrict__ attn) {
    const int lane = threadIdx.x & 63;
    const int wave = threadIdx.x >> 6;
    const int bh = blockIdx.z;           // b*16 + h
    const int h = bh & 15;
    const int m0 = (blockIdx.x * 4 + wave) * 16;
    const int n0 = blockIdx.y * 64;
    const int lr = lane & 15;
    const int lk = (lane >> 4) * 8;
    const bf16_t* ap = qb + (size_t)(bh >> 4) * 1024 * 1024 + (size_t)h * 64
                       + (size_t)(m0 + lr) * 1024 + lk;
    const bf16_t* bp = kbuf + (size_t)(bh >> 4) * 1024 * 1024 + (size_t)h * 64
                       + (size_t)(n0 + lr) * 1024 + lk;
    f32x4 acc[4] = {};
#pragma unroll
    for (int kb = 0; kb < 64; kb += 32) {
        bf16x8 a = *reinterpret_cast<const bf16x8*>(ap + kb);
#pragma unroll
        for (int f = 0; f < 4; ++f) {
            bf16x8 b = *reinterpret_cast<const bf16x8*>(bp + (size_t)f * 16 * 1024 + kb);
            acc[f] = MFMA16(a, b, acc[f]);
        }
    }
    float* orow = attn + (size_t)bh * 1024 * 1024;
    const float* brow = bias + (size_t)h * 1024 * 1024;
    const int rbase = m0 + (lane >> 4) * 4;
#pragma unroll
    for (int f = 0; f < 4; ++f) {
        const int col = n0 + f * 16 + lr;
#pragma unroll
        for (int r = 0; r < 4; ++r) {
            const size_t idx = (size_t)(rbase + r) * 1024 + col;
            orow[idx] = acc[f][r] + brow[idx];
        }
    }
}

// ---------------------------------------------------- in-place row softmax (1024)
__global__ __launch_bounds__(256) void softmax_rows(float* __restrict__ attn) {
    const size_t row = blockIdx.x;
    float4* p = reinterpret_cast<float4*>(attn + row * 1024);
    const int t = threadIdx.x;
    const int lane = t & 63, wid = t >> 6;
    float4 v = p[t];
    float m = fmaxf(fmaxf(v.x, v.y), fmaxf(v.z, v.w));
#pragma unroll
    for (int off = 32; off > 0; off >>= 1) m = fmaxf(m, __shfl_xor(m, off));
    __shared__ float sm[4], ss[4];
    if (lane == 0) sm[wid] = m;
    __syncthreads();
    m = fmaxf(fmaxf(sm[0], sm[1]), fmaxf(sm[2], sm[3]));
    float4 e;
    e.x = expf(v.x - m); e.y = expf(v.y - m); e.z = expf(v.z - m); e.w = expf(v.w - m);
    float s = e.x + e.y + e.z + e.w;
#pragma unroll
    for (int off = 32; off > 0; off >>= 1) s += __shfl_xor(s, off);
    if (lane == 0) ss[wid] = s;
    __syncthreads();
    s = ss[0] + ss[1] + ss[2] + ss[3];
    const float inv = 1.0f / s;
    v.x = e.x * inv; v.y = e.y * inv; v.z = e.z * inv; v.w = e.w * inv;
    p[t] = v;
}

// ------------------------------- ctx: per head attn[1024,1024] @ V[1024,64] (VT NT)
__global__ __launch_bounds__(256) void ctx_gemm(const float* __restrict__ attn,
                                                const bf16_t* __restrict__ vt,
                                                bf16_t* __restrict__ ctxb) {
    const int lane = threadIdx.x & 63;
    const int wave = threadIdx.x >> 6;
    const int bh = blockIdx.z, b = bh >> 4, h = bh & 15;
    const int m0 = (blockIdx.x * 4 + wave) * 16;
    const int lr = lane & 15;
    const int lk = (lane >> 4) * 8;
    const float* ap = attn + (size_t)bh * 1024 * 1024 + (size_t)(m0 + lr) * 1024 + lk;
    const bf16_t* bp = vt + (size_t)bh * 64 * 1024 + (size_t)lr * 1024 + lk;
    f32x4 acc[4] = {};
    for (int kb = 0; kb < 1024; kb += 32) {
        float4 u0 = *reinterpret_cast<const float4*>(ap + kb);
        float4 u1 = *reinterpret_cast<const float4*>(ap + kb + 4);
        bf16x8 a = { (bf16_t)u0.x, (bf16_t)u0.y, (bf16_t)u0.z, (bf16_t)u0.w,
                     (bf16_t)u1.x, (bf16_t)u1.y, (bf16_t)u1.z, (bf16_t)u1.w };
#pragma unroll
        for (int f = 0; f < 4; ++f) {
            bf16x8 bfr = *reinterpret_cast<const bf16x8*>(bp + (size_t)f * 16 * 1024 + kb);
            acc[f] = MFMA16(a, bfr, acc[f]);
        }
    }
    const int rbase = m0 + (lane >> 4) * 4;
#pragma unroll
    for (int f = 0; f < 4; ++f) {
        const int col = f * 16 + lr;   // dk index
#pragma unroll
        for (int r = 0; r < 4; ++r) {
            const int q = rbase + r;
            ctxb[(size_t)(b * 1024 + q) * 1024 + h * 64 + col] = (bf16_t)acc[f][r];
        }
    }
}

// ---------------------------------------------------------------------- launcher
extern "C" void kernel_launch(void* const* d_in, const int* in_sizes, int n_in,
                              void* d_out, int out_size, void* d_ws, size_t ws_size,
                              hipStream_t stream) {
    const float* x    = (const float*)d_in[0];
    const float* bias = (const float*)d_in[1];
    const float* Wq   = (const float*)d_in[2];
    const float* Wk   = (const float*)d_in[3];
    const float* Wv   = (const float*)d_in[4];
    const float* Wo   = (const float*)d_in[5];
    float* out  = (float*)d_out;
    float* attn = out + (size_t)4 * 1024 * 1024;

    char* ws = (char*)d_ws;
    bf16_t* xb   = (bf16_t*)(ws);                    //  8 MB  [4096,1024]
    bf16_t* wT   = (bf16_t*)(ws + ((size_t)8 << 20));  //  8 MB  4x [1024,1024] transposed
    bf16_t* qb   = (bf16_t*)(ws + ((size_t)16 << 20)); //  8 MB  Q/8 [B,S,D]
    bf16_t* kbuf = (bf16_t*)(ws + ((size_t)24 << 20)); //  8 MB  K   [B,S,D]
    bf16_t* vt   = (bf16_t*)(ws + ((size_t)32 << 20)); //  8 MB  VT  [B,H,DK,S]
    bf16_t* ctxb = (bf16_t*)(ws + ((size_t)40 << 20)); //  8 MB  ctx [B,S,D]
    bf16_t* wqT = wT;
    bf16_t* wkT = wT + ((size_t)1 << 20);
    bf16_t* wvT = wT + ((size_t)2 << 20);
    bf16_t* woT = wT + ((size_t)3 << 20);

    cast_f32_bf16<<<dim3(4096), dim3(256), 0, stream>>>(x, xb, 1024 * 1024);
    transpose_cast_w<<<dim3(32, 32, 4), dim3(32, 32), 0, stream>>>(Wq, Wk, Wv, Wo, wT);

    gemm_nt<0><<<dim3(64, 16), dim3(256), 0, stream>>>(xb, wqT, qb);
    gemm_nt<1><<<dim3(64, 16), dim3(256), 0, stream>>>(xb, wkT, kbuf);
    gemm_nt<2><<<dim3(64, 16), dim3(256), 0, stream>>>(xb, wvT, vt);

    scores_gemm<<<dim3(16, 16, 64), dim3(256), 0, stream>>>(qb, kbuf, bias, attn);
    softmax_rows<<<dim3(65536), dim3(256), 0, stream>>>(attn);
    ctx_gemm<<<dim3(16, 1, 64), dim3(256), 0, stream>>>(attn, vt, ctxb);
    gemm_nt<3><<<dim3(64, 16), dim3(256), 0, stream>>>(ctxb, woT, out);
}

// Round 2
// 345.850 us; speedup vs baseline: 1.7851x; 1.7851x over previous
//
#include <hip/hip_runtime.h>
#include <hip/hip_bf16.h>

// MHA forward: B=4, S=1024, D=1024, H=16, DK=64
// outputs: out [4,1024,1024] f32, attn [4,16,1024,1024] f32 (concat in d_out)

typedef __bf16 bf16_t;
typedef __bf16 bf16x4 __attribute__((ext_vector_type(4)));
typedef __bf16 bf16x8 __attribute__((ext_vector_type(8)));
typedef float f32x4 __attribute__((ext_vector_type(4)));

#define MFMA16(a, b, c) __builtin_amdgcn_mfma_f32_16x16x32_bf16(a, b, c, 0, 0, 0)

// ---------------------------------------------------------------- cast x -> bf16
__global__ __launch_bounds__(256) void cast_f32_bf16(const float* __restrict__ in,
                                                     bf16_t* __restrict__ out, int n4) {
    int i = blockIdx.x * blockDim.x + threadIdx.x;
    if (i >= n4) return;
    float4 v = reinterpret_cast<const float4*>(in)[i];
    bf16x4 o = { (bf16_t)v.x, (bf16_t)v.y, (bf16_t)v.z, (bf16_t)v.w };
    reinterpret_cast<bf16x4*>(out)[i] = o;
}

// ------------------------------------------- transpose + cast the 4 weight matrices
__global__ __launch_bounds__(1024) void transpose_cast_w(const float* __restrict__ w0,
                                                         const float* __restrict__ w1,
                                                         const float* __restrict__ w2,
                                                         const float* __restrict__ w3,
                                                         bf16_t* __restrict__ wt) {
    __shared__ float tile[32][33];
    const float* src = (blockIdx.z == 0) ? w0 : (blockIdx.z == 1) ? w1
                     : (blockIdx.z == 2) ? w2 : w3;
    bf16_t* dst = wt + (size_t)blockIdx.z * 1024 * 1024;
    int r0 = blockIdx.y * 32, c0 = blockIdx.x * 32;
    tile[threadIdx.y][threadIdx.x] = src[(size_t)(r0 + threadIdx.y) * 1024 + c0 + threadIdx.x];
    __syncthreads();
    dst[(size_t)(c0 + threadIdx.y) * 1024 + r0 + threadIdx.x] = (bf16_t)tile[threadIdx.x][threadIdx.y];
}

// ---------------------------------------------------- LDS-tiled NT GEMM, 128x64 tile
// A: [4096,1024] bf16 row-major; BT: [1024,1024] bf16 row-major ([N][K])
// block = 256 threads = 4 waves (2x2), each wave 64x32 output (4x2 frags of 16x16)
// BK=32. LDS XOR-swizzled in 16B slots: slot' = slot ^ ((row>>1)&3).
// MODE 0: store bf16 *0.125 (Q)  MODE 1: bf16 (K)
// MODE 2: bf16 transposed per head (V -> VT[b,h,dk,s])  MODE 3: f32 (out)
template <int MODE>
__global__ __launch_bounds__(256) void gemm_tile(const bf16_t* __restrict__ A,
                                                 const bf16_t* __restrict__ BT,
                                                 void* __restrict__ out) {
    __shared__ bf16_t As[128 * 32];
    __shared__ bf16_t Bs[64 * 32];
    const int tid = threadIdx.x;
    const int lane = tid & 63, wave = tid >> 6;
    const int lr = lane & 15, lg = lane >> 4;
    const int m_base = blockIdx.x * 128, n_base = blockIdx.y * 64;
    const int wm = (wave >> 1) * 64, wn = (wave & 1) * 32;

    // staging: 16B chunks; As has 512 chunks (2/thread), Bs has 256 (1/thread)
    const int ar0 = tid >> 2;             // As rows 0..63
    const int ar1 = 64 + (tid >> 2);      // As rows 64..127
    const int sl = tid & 3;               // k-slot 0..3
    const int asl0 = ((sl ^ ((ar0 >> 1) & 3)) * 8);
    const int asl1 = ((sl ^ ((ar1 >> 1) & 3)) * 8);
    const int bsl0 = asl0;                // same row parity pattern (ar0 == br0)

    const bf16_t* aptr0 = A + (size_t)(m_base + ar0) * 1024 + sl * 8;
    const bf16_t* aptr1 = A + (size_t)(m_base + ar1) * 1024 + sl * 8;
    const bf16_t* bptr  = BT + (size_t)(n_base + ar0) * 1024 + sl * 8;

    bf16x8 ra0 = *reinterpret_cast<const bf16x8*>(aptr0);
    bf16x8 ra1 = *reinterpret_cast<const bf16x8*>(aptr1);
    bf16x8 rb0 = *reinterpret_cast<const bf16x8*>(bptr);

    f32x4 acc[4][2] = {};
    for (int kb = 32; kb <= 1024; kb += 32) {
        __syncthreads();   // previous tile's ds_reads drained
        *reinterpret_cast<bf16x8*>(&As[ar0 * 32 + asl0]) = ra0;
        *reinterpret_cast<bf16x8*>(&As[ar1 * 32 + asl1]) = ra1;
        *reinterpret_cast<bf16x8*>(&Bs[ar0 * 32 + bsl0]) = rb0;
        if (kb < 1024) {   // prefetch next K-step while LDS settles
            ra0 = *reinterpret_cast<const bf16x8*>(aptr0 + kb);
            ra1 = *reinterpret_cast<const bf16x8*>(aptr1 + kb);
            rb0 = *reinterpret_cast<const bf16x8*>(bptr + kb);
        }
        __syncthreads();   // staging visible
        bf16x8 af[4], bfr[2];
#pragma unroll
        for (int i = 0; i < 4; ++i) {
            const int row = wm + i * 16 + lr;
            af[i] = *reinterpret_cast<const bf16x8*>(&As[row * 32 + ((lg ^ ((row >> 1) & 3)) * 8)]);
        }
#pragma unroll
        for (int j = 0; j < 2; ++j) {
            const int row = wn + j * 16 + lr;
            bfr[j] = *reinterpret_cast<const bf16x8*>(&Bs[row * 32 + ((lg ^ ((row >> 1) & 3)) * 8)]);
        }
#pragma unroll
        for (int i = 0; i < 4; ++i)
#pragma unroll
            for (int j = 0; j < 2; ++j)
                acc[i][j] = MFMA16(af[i], bfr[j], acc[i][j]);
    }

#pragma unroll
    for (int i = 0; i < 4; ++i)
#pragma unroll
        for (int j = 0; j < 2; ++j)
#pragma unroll
            for (int r = 0; r < 4; ++r) {
                const int row = m_base + wm + i * 16 + lg * 4 + r;
                const int col = n_base + wn + j * 16 + lr;
                const float v = acc[i][j][r];
                if (MODE == 0) {
                    ((bf16_t*)out)[(size_t)row * 1024 + col] = (bf16_t)(v * 0.125f);
                } else if (MODE == 1) {
                    ((bf16_t*)out)[(size_t)row * 1024 + col] = (bf16_t)v;
                } else if (MODE == 2) {
                    const int bb = row >> 10, s = row & 1023, hh = col >> 6, d = col & 63;
                    ((bf16_t*)out)[(((size_t)(bb * 16 + hh) * 64 + d) << 10) + s] = (bf16_t)v;
                } else {
                    ((float*)out)[(size_t)row * 1024 + col] = v;
                }
            }
}

// ------------------------------------------------ fused scores+bias+softmax+PV
// grid: 1024 blocks (XCD-aware decode), 256 threads = 4 waves, each wave 16 q-rows.
// Two passes over 16 K-tiles of 64: pass1 = online max/sum; pass2 = recompute,
// write normalized attn (f32, mandatory output) and accumulate ctx via LDS P-tile.
__global__ __launch_bounds__(256) void fused_attn(const bf16_t* __restrict__ qb,
                                                  const bf16_t* __restrict__ kbuf,
                                                  const bf16_t* __restrict__ vt,
                                                  const float* __restrict__ bias,
                                                  float* __restrict__ attn,
                                                  bf16_t* __restrict__ ctxb) {
    __shared__ bf16_t plds[4][2][16 * 72];   // per-wave double-buffered P tile
    const int lane = threadIdx.x & 63;
    const int wave = threadIdx.x >> 6;
    const int lr = lane & 15, lg = lane >> 4;

    // XCD-aware decode: pin each head's bias slab (4 MB) to one XCD's L2.
    const int blk = blockIdx.x;
    const int x7 = blk & 7, g = blk >> 3;
    const int h  = x7 + 8 * (g >> 6);     // 0..15
    const int qt = g & 15;                // q-tile
    const int b  = (g >> 4) & 3;          // batch
    const int bh = b * 16 + h;
    const int m0 = qt * 64 + wave * 16;

    const bf16_t* qp = qb + ((size_t)b << 20) + (size_t)(m0 + lr) * 1024 + h * 64 + lg * 8;
    bf16x8 aq0 = *reinterpret_cast<const bf16x8*>(qp);
    bf16x8 aq1 = *reinterpret_cast<const bf16x8*>(qp + 32);

    const bf16_t* kbase = kbuf + ((size_t)b << 20) + h * 64 + lg * 8;
    const float*  bbase = bias + ((size_t)h << 20);
    float*        obase = attn + ((size_t)bh << 20);
    const bf16_t* vbase = vt + (size_t)bh * (64 * 1024) + lg * 8;
    const int rbase = m0 + lg * 4;

    float m[4], l[4];
#pragma unroll
    for (int r = 0; r < 4; ++r) { m[r] = -1e30f; l[r] = 0.f; }

    // ---------------- pass 1: online max / sum
    for (int n0 = 0; n0 < 1024; n0 += 64) {
        f32x4 acc[4] = {};
        const bf16_t* kp = kbase + (size_t)(n0 + lr) * 1024;
#pragma unroll
        for (int f = 0; f < 4; ++f) {
            bf16x8 b0 = *reinterpret_cast<const bf16x8*>(kp + (size_t)f * 16 * 1024);
            bf16x8 b1 = *reinterpret_cast<const bf16x8*>(kp + (size_t)f * 16 * 1024 + 32);
            acc[f] = MFMA16(aq0, b0, acc[f]);
            acc[f] = MFMA16(aq1, b1, acc[f]);
        }
#pragma unroll
        for (int f = 0; f < 4; ++f) {
            const int col = n0 + f * 16 + lr;
#pragma unroll
            for (int r = 0; r < 4; ++r)
                acc[f][r] += bbase[(size_t)(rbase + r) * 1024 + col];
        }
#pragma unroll
        for (int r = 0; r < 4; ++r) {
            float tm = fmaxf(fmaxf(acc[0][r], acc[1][r]), fmaxf(acc[2][r], acc[3][r]));
            tm = fmaxf(tm, __shfl_xor(tm, 1));
            tm = fmaxf(tm, __shfl_xor(tm, 2));
            tm = fmaxf(tm, __shfl_xor(tm, 4));
            tm = fmaxf(tm, __shfl_xor(tm, 8));
            const float mn = fmaxf(m[r], tm);
            float ps = __expf(acc[0][r] - mn) + __expf(acc[1][r] - mn)
                     + __expf(acc[2][r] - mn) + __expf(acc[3][r] - mn);
            ps += __shfl_xor(ps, 1);
            ps += __shfl_xor(ps, 2);
            ps += __shfl_xor(ps, 4);
            ps += __shfl_xor(ps, 8);
            l[r] = l[r] * __expf(m[r] - mn) + ps;
            m[r] = mn;
        }
    }
    float invl[4];
#pragma unroll
    for (int r = 0; r < 4; ++r) invl[r] = 1.0f / l[r];

    // ---------------- pass 2: write attn, accumulate ctx
    f32x4 cacc[4] = {};
    for (int n0i = 0; n0i < 16; ++n0i) {
        const int n0 = n0i * 64;
        f32x4 acc[4] = {};
        const bf16_t* kp = kbase + (size_t)(n0 + lr) * 1024;
#pragma unroll
        for (int f = 0; f < 4; ++f) {
            bf16x8 b0 = *reinterpret_cast<const bf16x8*>(kp + (size_t)f * 16 * 1024);
            bf16x8 b1 = *reinterpret_cast<const bf16x8*>(kp + (size_t)f * 16 * 1024 + 32);
            acc[f] = MFMA16(aq0, b0, acc[f]);
            acc[f] = MFMA16(aq1, b1, acc[f]);
        }
        bf16_t* pw = &plds[wave][n0i & 1][0];
#pragma unroll
        for (int f = 0; f < 4; ++f) {
            const int col = n0 + f * 16 + lr;
#pragma unroll
            for (int r = 0; r < 4; ++r) {
                const size_t idx = (size_t)(rbase + r) * 1024 + col;
                const float p = __expf(acc[f][r] + bbase[idx] - m[r]) * invl[r];
                obase[idx] = p;
                pw[(lg * 4 + r) * 72 + f * 16 + lr] = (bf16_t)p;
            }
        }
        __syncthreads();   // drain LDS writes (own wave, cross-lane)
        const bf16_t* pr = &plds[wave][n0i & 1][0];
        bf16x8 pa0 = *reinterpret_cast<const bf16x8*>(pr + lr * 72 + lg * 8);
        bf16x8 pa1 = *reinterpret_cast<const bf16x8*>(pr + lr * 72 + 32 + lg * 8);
        const bf16_t* vp = vbase + n0;
#pragma unroll
        for (int f2 = 0; f2 < 4; ++f2) {
            bf16x8 v0 = *reinterpret_cast<const bf16x8*>(vp + (size_t)(f2 * 16 + lr) * 1024);
            bf16x8 v1 = *reinterpret_cast<const bf16x8*>(vp + (size_t)(f2 * 16 + lr) * 1024 + 32);
            cacc[f2] = MFMA16(pa0, v0, cacc[f2]);
            cacc[f2] = MFMA16(pa1, v1, cacc[f2]);
        }
    }
#pragma unroll
    for (int f2 = 0; f2 < 4; ++f2) {
        const int col = h * 64 + f2 * 16 + lr;
#pragma unroll
        for (int r = 0; r < 4; ++r)
            ctxb[(size_t)(b * 1024 + rbase + r) * 1024 + col] = (bf16_t)cacc[f2][r];
    }
}

// ---------------------------------------------------------------------- launcher
extern "C" void kernel_launch(void* const* d_in, const int* in_sizes, int n_in,
                              void* d_out, int out_size, void* d_ws, size_t ws_size,
                              hipStream_t stream) {
    const float* x    = (const float*)d_in[0];
    const float* bias = (const float*)d_in[1];
    const float* Wq   = (const float*)d_in[2];
    const float* Wk   = (const float*)d_in[3];
    const float* Wv   = (const float*)d_in[4];
    const float* Wo   = (const float*)d_in[5];
    float* out  = (float*)d_out;
    float* attn = out + (size_t)4 * 1024 * 1024;

    char* ws = (char*)d_ws;
    bf16_t* xb   = (bf16_t*)(ws);                      //  8 MB [4096,1024]
    bf16_t* wT   = (bf16_t*)(ws + ((size_t)8 << 20));  //  8 MB 4x [1024,1024] transposed
    bf16_t* qb   = (bf16_t*)(ws + ((size_t)16 << 20)); //  8 MB Q/8 [B,S,D]
    bf16_t* kbuf = (bf16_t*)(ws + ((size_t)24 << 20)); //  8 MB K   [B,S,D]
    bf16_t* vt   = (bf16_t*)(ws + ((size_t)32 << 20)); //  8 MB VT  [B,H,DK,S]
    bf16_t* ctxb = (bf16_t*)(ws + ((size_t)40 << 20)); //  8 MB ctx [B,S,D]
    bf16_t* wqT = wT;
    bf16_t* wkT = wT + ((size_t)1 << 20);
    bf16_t* wvT = wT + ((size_t)2 << 20);
    bf16_t* woT = wT + ((size_t)3 << 20);

    cast_f32_bf16<<<dim3(4096), dim3(256), 0, stream>>>(x, xb, 1024 * 1024);
    transpose_cast_w<<<dim3(32, 32, 4), dim3(32, 32), 0, stream>>>(Wq, Wk, Wv, Wo, wT);

    gemm_tile<0><<<dim3(32, 16), dim3(256), 0, stream>>>(xb, wqT, qb);
    gemm_tile<1><<<dim3(32, 16), dim3(256), 0, stream>>>(xb, wkT, kbuf);
    gemm_tile<2><<<dim3(32, 16), dim3(256), 0, stream>>>(xb, wvT, vt);

    fused_attn<<<dim3(1024), dim3(256), 0, stream>>>(qb, kbuf, vt, bias, attn, ctxb);

    gemm_tile<3><<<dim3(32, 16), dim3(256), 0, stream>>>(ctxb, woT, out);
}

// Round 3
// 263.621 us; speedup vs baseline: 2.3419x; 1.3119x over previous
//
#include <hip/hip_runtime.h>
#include <hip/hip_bf16.h>

// MHA forward: B=4, S=1024, D=1024, H=16, DK=64
// outputs: out [4,1024,1024] f32, attn [4,16,1024,1024] f32 (concat in d_out)

typedef __bf16 bf16_t;
typedef __bf16 bf16x4 __attribute__((ext_vector_type(4)));
typedef __bf16 bf16x8 __attribute__((ext_vector_type(8)));
typedef float f32x4 __attribute__((ext_vector_type(4)));

#define MFMA16(a, b, c) __builtin_amdgcn_mfma_f32_16x16x32_bf16(a, b, c, 0, 0, 0)

// ---------------------------------------------------------------- cast x -> bf16
__global__ __launch_bounds__(256) void cast_f32_bf16(const float* __restrict__ in,
                                                     bf16_t* __restrict__ out, int n4) {
    int i = blockIdx.x * blockDim.x + threadIdx.x;
    if (i >= n4) return;
    float4 v = reinterpret_cast<const float4*>(in)[i];
    bf16x4 o = { (bf16_t)v.x, (bf16_t)v.y, (bf16_t)v.z, (bf16_t)v.w };
    reinterpret_cast<bf16x4*>(out)[i] = o;
}

// ------------------------------------------- transpose + cast the 4 weight matrices
__global__ __launch_bounds__(1024) void transpose_cast_w(const float* __restrict__ w0,
                                                         const float* __restrict__ w1,
                                                         const float* __restrict__ w2,
                                                         const float* __restrict__ w3,
                                                         bf16_t* __restrict__ wt) {
    __shared__ float tile[32][33];
    const float* src = (blockIdx.z == 0) ? w0 : (blockIdx.z == 1) ? w1
                     : (blockIdx.z == 2) ? w2 : w3;
    bf16_t* dst = wt + (size_t)blockIdx.z * 1024 * 1024;
    int r0 = blockIdx.y * 32, c0 = blockIdx.x * 32;
    tile[threadIdx.y][threadIdx.x] = src[(size_t)(r0 + threadIdx.y) * 1024 + c0 + threadIdx.x];
    __syncthreads();
    dst[(size_t)(c0 + threadIdx.y) * 1024 + r0 + threadIdx.x] = (bf16_t)tile[threadIdx.x][threadIdx.y];
}

// ---------------------------------------------------- LDS-tiled NT GEMM, 128x64 tile
// (unchanged from round 2 — ~15 us each, revisit after fused_attn)
template <int MODE>
__global__ __launch_bounds__(256) void gemm_tile(const bf16_t* __restrict__ A,
                                                 const bf16_t* __restrict__ BT,
                                                 void* __restrict__ out) {
    __shared__ bf16_t As[128 * 32];
    __shared__ bf16_t Bs[64 * 32];
    const int tid = threadIdx.x;
    const int lane = tid & 63, wave = tid >> 6;
    const int lr = lane & 15, lg = lane >> 4;
    const int m_base = blockIdx.x * 128, n_base = blockIdx.y * 64;
    const int wm = (wave >> 1) * 64, wn = (wave & 1) * 32;

    const int ar0 = tid >> 2;
    const int ar1 = 64 + (tid >> 2);
    const int sl = tid & 3;
    const int asl0 = ((sl ^ ((ar0 >> 1) & 3)) * 8);
    const int asl1 = ((sl ^ ((ar1 >> 1) & 3)) * 8);
    const int bsl0 = asl0;

    const bf16_t* aptr0 = A + (size_t)(m_base + ar0) * 1024 + sl * 8;
    const bf16_t* aptr1 = A + (size_t)(m_base + ar1) * 1024 + sl * 8;
    const bf16_t* bptr  = BT + (size_t)(n_base + ar0) * 1024 + sl * 8;

    bf16x8 ra0 = *reinterpret_cast<const bf16x8*>(aptr0);
    bf16x8 ra1 = *reinterpret_cast<const bf16x8*>(aptr1);
    bf16x8 rb0 = *reinterpret_cast<const bf16x8*>(bptr);

    f32x4 acc[4][2] = {};
    for (int kb = 32; kb <= 1024; kb += 32) {
        __syncthreads();
        *reinterpret_cast<bf16x8*>(&As[ar0 * 32 + asl0]) = ra0;
        *reinterpret_cast<bf16x8*>(&As[ar1 * 32 + asl1]) = ra1;
        *reinterpret_cast<bf16x8*>(&Bs[ar0 * 32 + bsl0]) = rb0;
        if (kb < 1024) {
            ra0 = *reinterpret_cast<const bf16x8*>(aptr0 + kb);
            ra1 = *reinterpret_cast<const bf16x8*>(aptr1 + kb);
            rb0 = *reinterpret_cast<const bf16x8*>(bptr + kb);
        }
        __syncthreads();
        bf16x8 af[4], bfr[2];
#pragma unroll
        for (int i = 0; i < 4; ++i) {
            const int row = wm + i * 16 + lr;
            af[i] = *reinterpret_cast<const bf16x8*>(&As[row * 32 + ((lg ^ ((row >> 1) & 3)) * 8)]);
        }
#pragma unroll
        for (int j = 0; j < 2; ++j) {
            const int row = wn + j * 16 + lr;
            bfr[j] = *reinterpret_cast<const bf16x8*>(&Bs[row * 32 + ((lg ^ ((row >> 1) & 3)) * 8)]);
        }
#pragma unroll
        for (int i = 0; i < 4; ++i)
#pragma unroll
            for (int j = 0; j < 2; ++j)
                acc[i][j] = MFMA16(af[i], bfr[j], acc[i][j]);
    }

#pragma unroll
    for (int i = 0; i < 4; ++i)
#pragma unroll
        for (int j = 0; j < 2; ++j)
#pragma unroll
            for (int r = 0; r < 4; ++r) {
                const int row = m_base + wm + i * 16 + lg * 4 + r;
                const int col = n_base + wn + j * 16 + lr;
                const float v = acc[i][j][r];
                if (MODE == 0) {
                    ((bf16_t*)out)[(size_t)row * 1024 + col] = (bf16_t)(v * 0.125f);
                } else if (MODE == 1) {
                    ((bf16_t*)out)[(size_t)row * 1024 + col] = (bf16_t)v;
                } else if (MODE == 2) {
                    const int bb = row >> 10, s = row & 1023, hh = col >> 6, d = col & 63;
                    ((bf16_t*)out)[(((size_t)(bb * 16 + hh) * 64 + d) << 10) + s] = (bf16_t)v;
                } else {
                    ((float*)out)[(size_t)row * 1024 + col] = v;
                }
            }
}

// --------------------------------------- fused scores+bias+softmax+attn-write+PV
// ONE pass: block = 16 q-rows of one (b,h); 4 waves each own 256 k-cols held
// fully in registers (16 MFMA frags). Softmax = flat reduce (1 expf/element).
// P -> MFMA-A layout via per-wave XOR-swizzled LDS tile; ctx cross-wave reduce
// reuses the same LDS. Grid 4096, XCD-pinned so the 4 batches sharing a bias
// tile are consecutive on one XCD.
__global__ __launch_bounds__(256) void fused_attn(const bf16_t* __restrict__ qb,
                                                  const bf16_t* __restrict__ kbuf,
                                                  const bf16_t* __restrict__ vt,
                                                  const float* __restrict__ bias,
                                                  float* __restrict__ attn,
                                                  bf16_t* __restrict__ ctxb) {
    __shared__ bf16_t plds[4][4096];      // 32 KB: per-wave 16x256 P tile (swizzled)
    __shared__ float smax[4][16];
    __shared__ float ssum[4][16];

    const int lane = threadIdx.x & 63;
    const int wave = threadIdx.x >> 6;
    const int lr = lane & 15, lg = lane >> 4;

    // decode: g&7 = xcd slot; per-xcd order: b fastest (shares bias tile), then qt
    const int g = blockIdx.x;
    const int j = g >> 3;                  // 0..511
    const int h = (g & 7) + 8 * (j >> 8);  // 0..15
    const int qt = (j & 255) >> 2;         // 0..63
    const int b = j & 3;
    const int bh = b * 16 + h;
    const int m0 = qt * 16;

    // Q A-fragments (rows m0..m0+15, k = 0..63), Q pre-scaled by 1/8
    const bf16_t* qp = qb + ((size_t)b << 20) + (size_t)(m0 + lr) * 1024 + h * 64 + lg * 8;
    const bf16x8 aq0 = *reinterpret_cast<const bf16x8*>(qp);
    const bf16x8 aq1 = *reinterpret_cast<const bf16x8*>(qp + 32);

    const int c0 = wave * 256;             // this wave's k-col slice
    const bf16_t* kbase = kbuf + ((size_t)b << 20) + h * 64 + lg * 8;
    const float* bbase = bias + ((size_t)h << 20);
    const int rbase = m0 + lg * 4;

    // ---- QK^T + bias, scores stay in registers (16 frags = 64 VGPRs)
    f32x4 acc[16];
#pragma unroll
    for (int f = 0; f < 16; ++f) acc[f] = (f32x4){0.f, 0.f, 0.f, 0.f};

#pragma unroll
    for (int sub = 0; sub < 4; ++sub) {
        const int n0 = c0 + sub * 64;
        float breg[4][4];
#pragma unroll
        for (int f2 = 0; f2 < 4; ++f2) {
            const int col = n0 + f2 * 16 + lr;
#pragma unroll
            for (int r = 0; r < 4; ++r)
                breg[f2][r] = bbase[(size_t)(rbase + r) * 1024 + col];
        }
#pragma unroll
        for (int f2 = 0; f2 < 4; ++f2) {
            const int f = sub * 4 + f2;
            const bf16_t* kp = kbase + (size_t)(n0 + f2 * 16 + lr) * 1024;
            bf16x8 k0 = *reinterpret_cast<const bf16x8*>(kp);
            bf16x8 k1 = *reinterpret_cast<const bf16x8*>(kp + 32);
            acc[f] = MFMA16(aq0, k0, acc[f]);
            acc[f] = MFMA16(aq1, k1, acc[f]);
#pragma unroll
            for (int r = 0; r < 4; ++r) acc[f][r] += breg[f2][r];
        }
    }

    // ---- row max: in-lane (16 frags) -> shuffle over lr -> LDS cross-wave
    float mx[4];
#pragma unroll
    for (int r = 0; r < 4; ++r) {
        float m_ = acc[0][r];
#pragma unroll
        for (int f = 1; f < 16; ++f) m_ = fmaxf(m_, acc[f][r]);
        m_ = fmaxf(m_, __shfl_xor(m_, 1));
        m_ = fmaxf(m_, __shfl_xor(m_, 2));
        m_ = fmaxf(m_, __shfl_xor(m_, 4));
        m_ = fmaxf(m_, __shfl_xor(m_, 8));
        mx[r] = m_;
    }
    if (lr == 0) {
#pragma unroll
        for (int r = 0; r < 4; ++r) smax[wave][lg * 4 + r] = mx[r];
    }
    __syncthreads();
    float gm[4];
#pragma unroll
    for (int r = 0; r < 4; ++r) {
        const int row = lg * 4 + r;
        gm[r] = fmaxf(fmaxf(smax[0][row], smax[1][row]),
                      fmaxf(smax[2][row], smax[3][row]));
    }

    // ---- exp once per element + row sum
    float sm[4] = {0.f, 0.f, 0.f, 0.f};
#pragma unroll
    for (int f = 0; f < 16; ++f) {
#pragma unroll
        for (int r = 0; r < 4; ++r) {
            const float e = __expf(acc[f][r] - gm[r]);
            acc[f][r] = e;
            sm[r] += e;
        }
    }
#pragma unroll
    for (int r = 0; r < 4; ++r) {
        sm[r] += __shfl_xor(sm[r], 1);
        sm[r] += __shfl_xor(sm[r], 2);
        sm[r] += __shfl_xor(sm[r], 4);
        sm[r] += __shfl_xor(sm[r], 8);
    }
    if (lr == 0) {
#pragma unroll
        for (int r = 0; r < 4; ++r) ssum[wave][lg * 4 + r] = sm[r];
    }
    __syncthreads();
    float invl[4];
#pragma unroll
    for (int r = 0; r < 4; ++r) {
        const int row = lg * 4 + r;
        invl[r] = 1.0f / (ssum[0][row] + ssum[1][row] + ssum[2][row] + ssum[3][row]);
    }

    // ---- write normalized attn (f32, mandatory) + P tile to swizzled LDS
    float* obase = attn + ((size_t)bh << 20);
    char* pw = reinterpret_cast<char*>(&plds[wave][0]);
#pragma unroll
    for (int f = 0; f < 16; ++f) {
#pragma unroll
        for (int r = 0; r < 4; ++r) {
            const int row = lg * 4 + r;
            const float v = acc[f][r] * invl[r];
            obase[(size_t)(m0 + row) * 1024 + c0 + f * 16 + lr] = v;
            const int byteoff = row * 512 + ((f * 32 + lr * 2) ^ ((row & 7) << 4));
            *reinterpret_cast<bf16_t*>(pw + byteoff) = (bf16_t)v;
        }
    }
    __syncthreads();

    // ---- PV: partial ctx[16x64] over this wave's 256 cols
    const bf16_t* vbase = vt + (size_t)bh * (64 * 1024);
    f32x4 cacc[4];
#pragma unroll
    for (int f2 = 0; f2 < 4; ++f2) cacc[f2] = (f32x4){0.f, 0.f, 0.f, 0.f};
#pragma unroll
    for (int ks = 0; ks < 8; ++ks) {
        const int byteoff = lr * 512 + ((ks * 64 + lg * 16) ^ ((lr & 7) << 4));
        bf16x8 pa = *reinterpret_cast<const bf16x8*>(pw + byteoff);
        const bf16_t* vp = vbase + c0 + ks * 32 + lg * 8;
#pragma unroll
        for (int f2 = 0; f2 < 4; ++f2) {
            bf16x8 vf = *reinterpret_cast<const bf16x8*>(vp + (size_t)(f2 * 16 + lr) * 1024);
            cacc[f2] = MFMA16(pa, vf, cacc[f2]);
        }
    }
    __syncthreads();   // everyone done reading plds; re-alias as cred

    // ---- cross-wave ctx reduce via LDS (aliases plds)
    float* cred = reinterpret_cast<float*>(&plds[0][0]);   // [4][16][64]
#pragma unroll
    for (int f2 = 0; f2 < 4; ++f2)
#pragma unroll
        for (int r = 0; r < 4; ++r)
            cred[wave * 1024 + (lg * 4 + r) * 64 + f2 * 16 + lr] = cacc[f2][r];
    __syncthreads();
    const int row_l = wave * 4 + lg;       // wave handles 4 rows
    const int dk0 = lr * 4;
    f32x4 s0 = *reinterpret_cast<const f32x4*>(&cred[0 * 1024 + row_l * 64 + dk0]);
    f32x4 s1 = *reinterpret_cast<const f32x4*>(&cred[1 * 1024 + row_l * 64 + dk0]);
    f32x4 s2 = *reinterpret_cast<const f32x4*>(&cred[2 * 1024 + row_l * 64 + dk0]);
    f32x4 s3 = *reinterpret_cast<const f32x4*>(&cred[3 * 1024 + row_l * 64 + dk0]);
    f32x4 st = s0 + s1 + s2 + s3;
    bf16x4 o4 = { (bf16_t)st[0], (bf16_t)st[1], (bf16_t)st[2], (bf16_t)st[3] };
    *reinterpret_cast<bf16x4*>(
        &ctxb[(size_t)(b * 1024 + m0 + row_l) * 1024 + h * 64 + dk0]) = o4;
}

// ---------------------------------------------------------------------- launcher
extern "C" void kernel_launch(void* const* d_in, const int* in_sizes, int n_in,
                              void* d_out, int out_size, void* d_ws, size_t ws_size,
                              hipStream_t stream) {
    const float* x    = (const float*)d_in[0];
    const float* bias = (const float*)d_in[1];
    const float* Wq   = (const float*)d_in[2];
    const float* Wk   = (const float*)d_in[3];
    const float* Wv   = (const float*)d_in[4];
    const float* Wo   = (const float*)d_in[5];
    float* out  = (float*)d_out;
    float* attn = out + (size_t)4 * 1024 * 1024;

    char* ws = (char*)d_ws;
    bf16_t* xb   = (bf16_t*)(ws);                      //  8 MB [4096,1024]
    bf16_t* wT   = (bf16_t*)(ws + ((size_t)8 << 20));  //  8 MB 4x [1024,1024] transposed
    bf16_t* qb   = (bf16_t*)(ws + ((size_t)16 << 20)); //  8 MB Q/8 [B,S,D]
    bf16_t* kbuf = (bf16_t*)(ws + ((size_t)24 << 20)); //  8 MB K   [B,S,D]
    bf16_t* vt   = (bf16_t*)(ws + ((size_t)32 << 20)); //  8 MB VT  [B,H,DK,S]
    bf16_t* ctxb = (bf16_t*)(ws + ((size_t)40 << 20)); //  8 MB ctx [B,S,D]
    bf16_t* wqT = wT;
    bf16_t* wkT = wT + ((size_t)1 << 20);
    bf16_t* wvT = wT + ((size_t)2 << 20);
    bf16_t* woT = wT + ((size_t)3 << 20);

    cast_f32_bf16<<<dim3(4096), dim3(256), 0, stream>>>(x, xb, 1024 * 1024);
    transpose_cast_w<<<dim3(32, 32, 4), dim3(32, 32), 0, stream>>>(Wq, Wk, Wv, Wo, wT);

    gemm_tile<0><<<dim3(32, 16), dim3(256), 0, stream>>>(xb, wqT, qb);
    gemm_tile<1><<<dim3(32, 16), dim3(256), 0, stream>>>(xb, wkT, kbuf);
    gemm_tile<2><<<dim3(32, 16), dim3(256), 0, stream>>>(xb, wvT, vt);

    fused_attn<<<dim3(4096), dim3(256), 0, stream>>>(qb, kbuf, vt, bias, attn, ctxb);

    gemm_tile<3><<<dim3(32, 16), dim3(256), 0, stream>>>(ctxb, woT, out);
}